// Round 4
// baseline (3179.507 us; speedup 1.0000x reference)
//
#include <hip/hip_runtime.h>
#include <hip/hip_bf16.h>
#include <cstdint>

typedef unsigned int u32;
typedef unsigned short u16;
typedef __bf16 bf16x8 __attribute__((ext_vector_type(8)));
typedef float f32x4 __attribute__((ext_vector_type(4)));
typedef u16 u16x8 __attribute__((ext_vector_type(8)));

#define T_STEPS 512
#define NGRP 4            // batch groups (16 batches each)
#define GQ 16             // blocks per group per layer (each owns 16 h-dims)
#define HR 4              // h ring slots (peers stay within 1 step -> 4 is safe)
#define XR 64             // hs0 ring slots (backpressure keeps L0 lead < 48)
#define HSLOT (64 * 256)  // u32 per h-ring slot  [64 batch][256 dim]
#define XSLOT (64 * 256)  // u32 per x-ring slot

#define HBUF0_OFF (64u * 1024u)
#define HBUF_BYTES (HR * HSLOT * 4)
#define HBUF1_OFF (HBUF0_OFF + HBUF_BYTES)
#define XRING_OFF (1u << 20)
#define XRING_BYTES (XR * XSLOT * 4)
#define WS_NEEDED (XRING_OFF + XRING_BYTES)

__device__ __forceinline__ float sigm(float z) { return 1.f / (1.f + __expf(-z)); }
__device__ __forceinline__ float tanh_(float z) { return 1.f - 2.f / (__expf(2.f * z) + 1.f); }
__device__ __forceinline__ u16 f2bf(float f) {
    union { __bf16 b; u16 u; } v; v.b = (__bf16)f; return v.u;
}
// Relaxed agent-scope atomics: agent-coherent, no L2 sweeps, no ordering cost.
// Every cross-block word is self-describing (value | tag) so NO fences exist.
__device__ __forceinline__ u32 gload(const u32* p) {
    return __hip_atomic_load(p, __ATOMIC_RELAXED, __HIP_MEMORY_SCOPE_AGENT);
}
__device__ __forceinline__ void gstore(u32* p, u32 v) {
    __hip_atomic_store(p, v, __ATOMIC_RELAXED, __HIP_MEMORY_SCOPE_AGENT);
}

// Block (layer, grp, q): batches [16*grp,16*grp+16), h-dims [16*q,16*q+16).
// 256 threads = 4 waves; wave w owns dims [4w,4w+4) x 4 gates (one 16-wide MFMA N-tile).
// Tagged-word protocol: hring[s%HR][batch][dim] holds bf16(h_s)|s<<16.
template <int KX, bool L0>
__device__ void lstm_body(
    int grp, int q,
    const float* __restrict__ xf,   // layer0 input x [64][512][128] f32
    const float* __restrict__ W,    // [1024][256+KX] f32 (cols: [h | x])
    const float* __restrict__ bias, // [1024]
    u32* __restrict__ prog,         // [NGRP][GQ] L1 progress (stride 16 u32)
    u32* __restrict__ hring,        // own layer h ring [HR][64][256] tagged u32
    u32* __restrict__ xring,        // hs0 ring [XR][64][256] tagged u32
    float* __restrict__ out,
    u16* A_lds, float* D_lds)
{
    constexpr int K = 256 + KX;
    constexpr int NT = K / 32;      // k-tiles
    constexpr int LDA = K + 8;      // u16 per A_lds row (pad)
    constexpr int ABUF = 16 * LDA;  // u16 per A buffer

    const int tid = threadIdx.x;
    const int wave = tid >> 6;
    const int lane = tid & 63;
    const int g = lane >> 4;
    const int n = lane & 15;

    // ---- weights -> register B-fragments (one-time) ----
    const int wrow = (n >> 2) * 256 + q * 16 + (wave << 2) + (n & 3);
    bf16x8 wfrag[NT];
    {
        const float* Wr = W + (long)wrow * K;
#pragma unroll
        for (int kt = 0; kt < NT; ++kt) {
            const float* p = Wr + kt * 32 + g * 8;
            float4 lo = *(const float4*)p;
            float4 hi = *(const float4*)(p + 4);
            bf16x8 f;
            f[0] = (__bf16)lo.x; f[1] = (__bf16)lo.y; f[2] = (__bf16)lo.z; f[3] = (__bf16)lo.w;
            f[4] = (__bf16)hi.x; f[5] = (__bf16)hi.y; f[6] = (__bf16)hi.z; f[7] = (__bf16)hi.w;
            wfrag[kt] = f;
        }
    }
    const float bias_n = bias[wrow];

    // elementwise identity: lane -> (batch eb, local dim 4*wave+edd), all 4 gates
    const int eb = lane & 15;
    const int edd = lane >> 4;
    const int dim_local = (wave << 2) + edd;
    float c_state = 0.f;

    // publish pointers (this lane's single tagged word per step)
    u32* hpub = hring + ((grp * 16 + eb) * 256 + q * 16 + dim_local);
    u32* xpub = xring + ((grp * 16 + eb) * 256 + q * 16 + dim_local);

    // consumer identity: thread (sb,sseg) loads batch sb, dims [16*sseg,16*sseg+16)
    const int sb = tid >> 4;
    const int sseg = tid & 15;
    const u32* hcon = hring + ((grp * 16 + sb) * 256 + sseg * 16);
    const u32* xcon = xring + ((grp * 16 + sb) * 256 + sseg * 16);

    auto stage_x = [&](int t) {  // L0 only: x(t) f32 -> bf16 into buf[t&1] x-region
        if constexpr (L0) {
            const float* p = xf + ((long)(grp * 16 + sb) * T_STEPS + t) * 128 + sseg * 8;
            float4 lo = *(const float4*)p;
            float4 hi = *(const float4*)(p + 4);
            u16x8 v;
            v[0] = f2bf(lo.x); v[1] = f2bf(lo.y); v[2] = f2bf(lo.z); v[3] = f2bf(lo.w);
            v[4] = f2bf(hi.x); v[5] = f2bf(hi.y); v[6] = f2bf(hi.z); v[7] = f2bf(hi.w);
            *(u16x8*)&A_lds[(t & 1) * ABUF + sb * LDA + 256 + sseg * 8] = v;
        }
    };

    stage_x(0);

    for (int s = 0; s < T_STEPS; ++s) {
        u16* Abuf = A_lds + (s & 1) * ABUF;
        u32* Arow32 = (u32*)(Abuf + sb * LDA);

        // ---- L0 backpressure on hs0 ring (rarely binds; 16 pollers gate the block) ----
        if constexpr (L0) {
            if ((s & 15) == 0 && s >= 48 && tid < 16) {
                const u32 need = (u32)(s - 40);
                const u32* pp = prog + (grp * GQ + tid) * 16;
                int gu = 0;
                while (gload(pp) < need && ++gu < (1 << 15)) {}
            }
        }

        // ---- poll tagged h(s) (+ hs0(s) for L1): arrival IS notification ----
        {
            const u32* hp = hcon + (s & (HR - 1)) * HSLOT;
            u32 wv[16];
            if constexpr (!L0) {
                const u32* xp = xcon + ((s + 1) & (XR - 1)) * XSLOT;
                u32 xv[16];
                const u32 ht = (u32)s, xt = (u32)(s + 1);
                int gu = 0;
                for (;;) {
                    u32 bad = 0;
#pragma unroll
                    for (int j = 0; j < 16; ++j) wv[j] = gload(hp + j);
#pragma unroll
                    for (int j = 0; j < 16; ++j) xv[j] = gload(xp + j);
#pragma unroll
                    for (int j = 0; j < 16; ++j) {
                        bad |= (wv[j] >> 16) ^ ht;
                        bad |= (xv[j] >> 16) ^ xt;
                    }
                    if (!bad) break;
                    if (++gu > (1 << 15)) break;
                }
#pragma unroll
                for (int j = 0; j < 8; ++j)
                    Arow32[128 + sseg * 8 + j] = (xv[2 * j] & 0xffffu) | (xv[2 * j + 1] << 16);
            } else {
                const u32 ht = (u32)s;
                int gu = 0;
                for (;;) {
                    u32 bad = 0;
#pragma unroll
                    for (int j = 0; j < 16; ++j) wv[j] = gload(hp + j);
#pragma unroll
                    for (int j = 0; j < 16; ++j) bad |= (wv[j] >> 16) ^ ht;
                    if (!bad) break;
                    if (++gu > (1 << 15)) break;
                }
            }
#pragma unroll
            for (int j = 0; j < 8; ++j)
                Arow32[sseg * 8 + j] = (wv[2 * j] & 0xffffu) | (wv[2 * j + 1] << 16);
        }
        __syncthreads();   // the ONE barrier per step: A-tile staged

        // ---- L1: publish progress (all x(s) reads complete past the barrier) ----
        if constexpr (!L0) {
            if (tid == 0) gstore(prog + (grp * GQ + q) * 16, (u32)(s + 1));
        }

        // ---- MFMA, 4 accumulator chains to cut dependent latency ----
        f32x4 a0 = {bias_n, bias_n, bias_n, bias_n};
        f32x4 a1 = {0.f, 0.f, 0.f, 0.f}, a2 = a1, a3 = a1;
#pragma unroll
        for (int kt = 0; kt < NT; ++kt) {
            bf16x8 af = __builtin_bit_cast(
                bf16x8, *(const u16x8*)&Abuf[n * LDA + kt * 32 + g * 8]);
            if ((kt & 3) == 0)      a0 = __builtin_amdgcn_mfma_f32_16x16x32_bf16(af, wfrag[kt], a0, 0, 0, 0);
            else if ((kt & 3) == 1) a1 = __builtin_amdgcn_mfma_f32_16x16x32_bf16(af, wfrag[kt], a1, 0, 0, 0);
            else if ((kt & 3) == 2) a2 = __builtin_amdgcn_mfma_f32_16x16x32_bf16(af, wfrag[kt], a2, 0, 0, 0);
            else                    a3 = __builtin_amdgcn_mfma_f32_16x16x32_bf16(af, wfrag[kt], a3, 0, 0, 0);
        }
        f32x4 acc = (a0 + a1) + (a2 + a3);

        // ---- regroup via wave-local LDS: lane -> (batch, dim) holding 4 gates ----
#pragma unroll
        for (int r = 0; r < 4; ++r)
            D_lds[wave * 272 + n * 17 + g * 4 + r] = acc[r];
        float ga[4];
#pragma unroll
        for (int aa = 0; aa < 4; ++aa)
            ga[aa] = D_lds[wave * 272 + (aa * 4 + edd) * 17 + eb];

        // ---- elementwise (gate order: f, i, o, g) ----
        float fg = sigm(ga[0]);
        float ig = sigm(ga[1]);
        float og = sigm(ga[2]);
        float gg = tanh_(ga[3]);
        c_state = fg * c_state + ig * gg;
        float h_new = og * tanh_(c_state);

        // ---- publish immediately from the owning lane (no LDS hop, no barrier) ----
        const u32 tagged = (u32)f2bf(h_new) | ((u32)(s + 1) << 16);
        gstore(hpub + ((s + 1) & (HR - 1)) * HSLOT, tagged);
        if constexpr (L0)
            gstore(xpub + ((s + 1) & (XR - 1)) * XSLOT, tagged);

        if (s == T_STEPS - 1) {
            const int o1 = (grp * 16 + eb) * 256 + q * 16 + dim_local;
            if constexpr (L0) {
                out[16384 + o1] = h_new;   // h_n[0]
                out[49152 + o1] = c_state; // c_n[0]
            } else {
                out[o1] = h_new;           // h1T
                out[32768 + o1] = h_new;   // h_n[1]
                out[65536 + o1] = c_state; // c_n[1]
            }
        }

        // L0: prefetch x into next buf — GUARDED (t=512 would read past x's end)
        if (s + 1 < T_STEPS) stage_x(s + 1);
    }
}

__global__ __launch_bounds__(256, 1) void lstm_fused(
    const float* __restrict__ xf,
    const float* __restrict__ W0, const float* __restrict__ b0,
    const float* __restrict__ W1, const float* __restrict__ b1,
    u32* __restrict__ prog,
    u32* __restrict__ hbuf0, u32* __restrict__ hbuf1,
    u32* __restrict__ xring,
    float* __restrict__ out)
{
    __shared__ u16 A_lds[2 * 16 * 520];    // double-buffered; max LDA = 512+8
    __shared__ float D_lds[4 * 16 * 17];

    const int bid = blockIdx.x;
    if (bid < 64) {
        lstm_body<128, true >(bid >> 4, bid & 15, xf, W0, b0, prog, hbuf0, xring, out,
                              A_lds, D_lds);
    } else {
        const int b2 = bid - 64;
        lstm_body<256, false>(b2 >> 4, b2 & 15, nullptr, W1, b1, prog, hbuf1, xring, out,
                              A_lds, D_lds);
    }
}

extern "C" void kernel_launch(void* const* d_in, const int* in_sizes, int n_in,
                              void* d_out, int out_size, void* d_ws, size_t ws_size,
                              hipStream_t stream) {
    (void)in_sizes; (void)n_in; (void)out_size;
    const float* x  = (const float*)d_in[0];
    const float* W0 = (const float*)d_in[1];
    const float* b0 = (const float*)d_in[2];
    const float* W1 = (const float*)d_in[3];
    const float* b1 = (const float*)d_in[4];
    float* out = (float*)d_out;

    char* ws = (char*)d_ws;
    u32* prog  = (u32*)ws;
    u32* hbuf0 = (u32*)(ws + HBUF0_OFF);
    u32* hbuf1 = (u32*)(ws + HBUF1_OFF);
    u32* xring = (u32*)(ws + XRING_OFF);

    if (ws_size < WS_NEEDED) return;

    // Zero rings+prog each call: tag 0 == step 0 gives h(0)=0 for free, and
    // clears stale tags from the previous replay (slot j can hold tag==j mod R).
    hipMemsetAsync(d_ws, 0, WS_NEEDED, stream);

    lstm_fused<<<128, 256, 0, stream>>>(x, W0, b0, W1, b1, prog, hbuf0, hbuf1, xring, out);
}

// Round 5
// 3055.614 us; speedup vs baseline: 1.0405x; 1.0405x over previous
//
#include <hip/hip_runtime.h>
#include <hip/hip_bf16.h>
#include <cstdint>

typedef unsigned int u32;
typedef unsigned short u16;
typedef __bf16 bf16x8 __attribute__((ext_vector_type(8)));
typedef float f32x4 __attribute__((ext_vector_type(4)));
typedef u16 u16x8 __attribute__((ext_vector_type(8)));
typedef u16 u16x4 __attribute__((ext_vector_type(4)));
typedef u32 u32x4 __attribute__((ext_vector_type(4)));

#define T_STEPS 512
#define NGRP 4            // batch groups (16 batches each)
#define GQ 4              // fat blocks per (layer,group); each owns 64 h-dims
#define HR 4              // h ring slots (peer spread <=1 step)
#define XR 64             // hs0 ring slots (backpressure keeps lead < 41)
#define HSLOT (64 * 256)  // u32 per h-ring slot [64 batch][256 dim]
#define XSLOT (64 * 256)

#define HBUF0_OFF (64u * 1024u)
#define HBUF_BYTES (HR * HSLOT * 4)
#define HBUF1_OFF (HBUF0_OFF + HBUF_BYTES)
#define XRING_OFF (1u << 20)
#define XRING_BYTES (XR * XSLOT * 4)
#define WS_NEEDED (XRING_OFF + XRING_BYTES)

__device__ __forceinline__ float sigm(float z) { return 1.f / (1.f + __expf(-z)); }
__device__ __forceinline__ float tanh_(float z) { return 1.f - 2.f / (__expf(2.f * z) + 1.f); }
__device__ __forceinline__ u16 f2bf(float f) {
    union { __bf16 b; u16 u; } v; v.b = (__bf16)f; return v.u;
}
// Relaxed agent-scope atomics: agent-coherent, no L2 sweeps, no fences anywhere.
// Every cross-block word is self-describing: bf16(value) | (step_tag << 16).
__device__ __forceinline__ u32 gload(const u32* p) {
    return __hip_atomic_load(p, __ATOMIC_RELAXED, __HIP_MEMORY_SCOPE_AGENT);
}
__device__ __forceinline__ void gstore(u32* p, u32 v) {
    __hip_atomic_store(p, v, __ATOMIC_RELAXED, __HIP_MEMORY_SCOPE_AGENT);
}

// Block (layer, grp, q): batches [16*grp..+16), h-dims [64*q..+64).
// 512 threads = 8 waves. Wave w owns dims [8w..8w+8) x 4 gates = two 16-col n-tiles
// (tile0: dims 8w+0..3, tile1: dims 8w+4..7), so elementwise stays wave-local.
template <int KX, bool L0>
__device__ void lstm_body(
    int grp, int q,
    const float* __restrict__ xf,   // layer0 input x [64][512][128] f32
    const float* __restrict__ W,    // [1024][256+KX] f32 (cols: [h | x])
    const float* __restrict__ bias, // [1024]
    u32* __restrict__ prog,         // [NGRP][GQ] L1 progress (stride 16 u32)
    u32* __restrict__ hring,        // own-layer h ring [HR][64][256] tagged u32
    u32* __restrict__ xring,        // hs0 ring [XR][64][256] tagged u32
    float* __restrict__ out,
    u16* A_lds, float* D_lds)
{
    constexpr int K = 256 + KX;
    constexpr int NT = K / 32;
    constexpr int LDA = K + 8;       // u16 per A row (pad)
    constexpr int ABUF = 16 * LDA;   // u16 per A buffer

    const int tid = threadIdx.x;     // 0..511
    const int wave = tid >> 6;       // 0..7
    const int lane = tid & 63;
    const int g = lane >> 4;         // k-chunk 0..3
    const int n = lane & 15;         // tile column

    // ---- weights -> register B-fragments for the wave's two n-tiles ----
    const int a_gate = n >> 2, dd = n & 3;
    const int wrow0 = a_gate * 256 + q * 64 + 8 * wave + dd;   // tile0: dim dd
    const int wrow1 = wrow0 + 4;                               // tile1: dim dd+4
    bf16x8 wf0[NT], wf1[NT];
    {
        const float* r0 = W + (long)wrow0 * K;
        const float* r1 = W + (long)wrow1 * K;
#pragma unroll
        for (int kt = 0; kt < NT; ++kt) {
            const float* p0 = r0 + kt * 32 + g * 8;
            const float* p1 = r1 + kt * 32 + g * 8;
            float4 a = *(const float4*)p0, b = *(const float4*)(p0 + 4);
            float4 c = *(const float4*)p1, d = *(const float4*)(p1 + 4);
            bf16x8 f0, f1;
            f0[0]=(__bf16)a.x; f0[1]=(__bf16)a.y; f0[2]=(__bf16)a.z; f0[3]=(__bf16)a.w;
            f0[4]=(__bf16)b.x; f0[5]=(__bf16)b.y; f0[6]=(__bf16)b.z; f0[7]=(__bf16)b.w;
            f1[0]=(__bf16)c.x; f1[1]=(__bf16)c.y; f1[2]=(__bf16)c.z; f1[3]=(__bf16)c.w;
            f1[4]=(__bf16)d.x; f1[5]=(__bf16)d.y; f1[6]=(__bf16)d.z; f1[7]=(__bf16)d.w;
            wf0[kt] = f0; wf1[kt] = f1;
        }
    }
    const float bias0 = bias[wrow0];
    const float bias1 = bias[wrow1];

    // elementwise identity: lane -> (batch eb, dims 8w+edd and 8w+4+edd)
    const int eb = lane & 15;
    const int edd = lane >> 4;
    float c0 = 0.f, c1 = 0.f;
    const int pub_base = (grp * 16 + eb) * 256 + q * 64 + 8 * wave + edd;

    // consumer identity: thread (sb, seg) handles batch sb, dims [8*seg..+8)
    const int sb = tid >> 5;
    const int seg = tid & 31;
    const u32* hcon = hring + ((grp * 16 + sb) * 256 + seg * 8);
    const u32* xcon = xring + ((grp * 16 + sb) * 256 + seg * 8);

    auto stage_x = [&](int t) {  // L0: x(t) f32 -> bf16 into buf[t&1] cols 256..383
        if constexpr (L0) {
            const float* p = xf + ((long)(grp * 16 + sb) * T_STEPS + t) * 128 + seg * 4;
            float4 v = *(const float4*)p;
            u16x4 h; h[0]=f2bf(v.x); h[1]=f2bf(v.y); h[2]=f2bf(v.z); h[3]=f2bf(v.w);
            *(u16x4*)&A_lds[(t & 1) * ABUF + sb * LDA + 256 + seg * 4] = h;
        }
    };
    auto stage_xr = [&](int t) {  // L1: validated read of hs0 tag t+1 -> buf[t&1]
        if constexpr (!L0) {
            const u32 xt = (u32)(t + 1);
            const u32* xp = xcon + ((size_t)((t + 1) & (XR - 1))) * XSLOT;
            u32 tw[8]; int gu = 0;
            for (;;) {
#pragma unroll
                for (int j = 0; j < 8; ++j) tw[j] = gload(xp + j);
                u32 bad = 0;
#pragma unroll
                for (int j = 0; j < 8; ++j) bad |= (tw[j] >> 16) ^ xt;
                if (!bad) break;
                if (++gu > (1 << 17)) break;
            }
            u32x4 w;
#pragma unroll
            for (int j = 0; j < 4; ++j) w[j] = (tw[2 * j] & 0xffffu) | (tw[2 * j + 1] << 16);
            u32* Arow = (u32*)(A_lds + (t & 1) * ABUF + sb * LDA);
            *(u32x4*)&Arow[128 + seg * 4] = w;
        }
    };

    // prologue: input for iteration 0
    if constexpr (L0) stage_x(0); else stage_xr(0);

    for (int s = 0; s < T_STEPS; ++s) {
        u16* Abuf = A_lds + (s & 1) * ABUF;

        // ---- L0 backpressure on hs0 ring (checked every 16 steps, rarely binds) ----
        if constexpr (L0) {
            if ((s & 15) == 0 && s >= 48 && tid < GQ) {
                const u32 need = (u32)(s - 40);
                const u32* pp = prog + (grp * GQ + tid) * 16;
                int gu = 0;
                while (gload(pp) < need && ++gu < (1 << 17)) {}
            }
        }

        // ---- probe: 4 threads watch 1 representative word per producer ----
        if (tid < GQ) {
            const u32* pp = hring + (size_t)(s & (HR - 1)) * HSLOT
                          + (grp * 16 + 15) * 256 + tid * 64 + 63;
            int gu = 0;
            while ((gload(pp) >> 16) != (u32)s && ++gu < (1 << 17)) {}
        }
        __syncthreads();

        // ---- validated full read of h(s) (usually 1 iteration) + LDS stage ----
        {
            const u32* hp = hcon + (size_t)(s & (HR - 1)) * HSLOT;
            u32 tw[8]; int gu = 0;
            for (;;) {
#pragma unroll
                for (int j = 0; j < 8; ++j) tw[j] = gload(hp + j);
                u32 bad = 0;
#pragma unroll
                for (int j = 0; j < 8; ++j) bad |= (tw[j] >> 16) ^ (u32)s;
                if (!bad) break;
                if (++gu > (1 << 15)) break;
            }
            u32x4 w;
#pragma unroll
            for (int j = 0; j < 4; ++j) w[j] = (tw[2 * j] & 0xffffu) | (tw[2 * j + 1] << 16);
            u32* Arow = (u32*)(Abuf + sb * LDA);
            *(u32x4*)&Arow[seg * 4] = w;
        }
        __syncthreads();

        // ---- MFMA: two n-tiles, 2 chains each (4 independent streams) ----
        f32x4 c00 = {bias0, bias0, bias0, bias0}, c01 = {0.f, 0.f, 0.f, 0.f};
        f32x4 c10 = {bias1, bias1, bias1, bias1}, c11 = {0.f, 0.f, 0.f, 0.f};
#pragma unroll
        for (int kt = 0; kt < NT; ++kt) {
            bf16x8 af = __builtin_bit_cast(
                bf16x8, *(const u16x8*)&Abuf[n * LDA + kt * 32 + g * 8]);
            if (kt & 1) {
                c01 = __builtin_amdgcn_mfma_f32_16x16x32_bf16(af, wf0[kt], c01, 0, 0, 0);
                c11 = __builtin_amdgcn_mfma_f32_16x16x32_bf16(af, wf1[kt], c11, 0, 0, 0);
            } else {
                c00 = __builtin_amdgcn_mfma_f32_16x16x32_bf16(af, wf0[kt], c00, 0, 0, 0);
                c10 = __builtin_amdgcn_mfma_f32_16x16x32_bf16(af, wf1[kt], c10, 0, 0, 0);
            }
        }
        f32x4 acc0 = c00 + c01, acc1 = c10 + c11;

        // ---- regroup via wave-local LDS (no barrier needed) ----
#pragma unroll
        for (int r = 0; r < 4; ++r) {
            D_lds[wave * 544 + n * 17 + g * 4 + r] = acc0[r];
            D_lds[wave * 544 + 272 + n * 17 + g * 4 + r] = acc1[r];
        }
        float ga0[4], ga1[4];
#pragma unroll
        for (int a = 0; a < 4; ++a) {
            ga0[a] = D_lds[wave * 544 + (a * 4 + edd) * 17 + eb];
            ga1[a] = D_lds[wave * 544 + 272 + (a * 4 + edd) * 17 + eb];
        }

        // ---- elementwise, 2 (batch,dim) pairs per lane (gate order f,i,o,g) ----
        float h0, h1;
        {
            float fg = sigm(ga0[0]), ig = sigm(ga0[1]), og = sigm(ga0[2]), gg = tanh_(ga0[3]);
            c0 = fg * c0 + ig * gg; h0 = og * tanh_(c0);
            fg = sigm(ga1[0]); ig = sigm(ga1[1]); og = sigm(ga1[2]); gg = tanh_(ga1[3]);
            c1 = fg * c1 + ig * gg; h1 = og * tanh_(c1);
        }

        // ---- publish h(s+1): tagged fire-and-forget, no fences, no barrier ----
        const u32 tag = (u32)(s + 1) << 16;
        {
            u32* hs_ = hring + (size_t)((s + 1) & (HR - 1)) * HSLOT + pub_base;
            gstore(hs_, tag | f2bf(h0));
            gstore(hs_ + 4, tag | f2bf(h1));
            if constexpr (L0) {
                u32* xs_ = xring + (size_t)((s + 1) & (XR - 1)) * XSLOT + pub_base;
                gstore(xs_, tag | f2bf(h0));
                gstore(xs_ + 4, tag | f2bf(h1));
            }
        }

        if (s == T_STEPS - 1) {
            const int o1 = pub_base;   // (grp*16+eb)*256 + q*64 + 8w + edd
            if constexpr (L0) {
                out[16384 + o1] = h0;     out[16384 + o1 + 4] = h1;   // h_n[0]
                out[49152 + o1] = c0;     out[49152 + o1 + 4] = c1;   // c_n[0]
            } else {
                out[o1] = h0;             out[o1 + 4] = h1;           // h1T
                out[32768 + o1] = h0;     out[32768 + o1 + 4] = h1;   // h_n[1]
                out[65536 + o1] = c0;     out[65536 + o1 + 4] = c1;   // c_n[1]
            }
        }

        // ---- next-step input staging, off the critical path ----
        if constexpr (L0) {
            if (s + 1 < T_STEPS) stage_x(s + 1);  // guarded: t=512 would be OOB
        } else {
            if (s + 1 < T_STEPS) stage_xr(s + 1);
            if (tid == 0) gstore(prog + (grp * GQ + q) * 16, (u32)(s + 1));
        }
    }
}

__global__ __launch_bounds__(512, 2) void lstm_fused(
    const float* __restrict__ xf,
    const float* __restrict__ W0, const float* __restrict__ b0,
    const float* __restrict__ W1, const float* __restrict__ b1,
    u32* __restrict__ prog,
    u32* __restrict__ hbuf0, u32* __restrict__ hbuf1,
    u32* __restrict__ xring,
    float* __restrict__ out)
{
    __shared__ u16 A_lds[2 * 16 * 520];    // double-buffered; max LDA = 512+8
    __shared__ float D_lds[8 * 544];       // per-wave 2-tile regroup regions

    const int bid = blockIdx.x;
    if (bid < 16) {
        lstm_body<128, true >(bid >> 2, bid & 3, xf, W0, b0, prog, hbuf0, xring, out,
                              A_lds, D_lds);
    } else {
        const int b2 = bid - 16;
        lstm_body<256, false>(b2 >> 2, b2 & 3, nullptr, W1, b1, prog, hbuf1, xring, out,
                              A_lds, D_lds);
    }
}

extern "C" void kernel_launch(void* const* d_in, const int* in_sizes, int n_in,
                              void* d_out, int out_size, void* d_ws, size_t ws_size,
                              hipStream_t stream) {
    (void)in_sizes; (void)n_in; (void)out_size;
    const float* x  = (const float*)d_in[0];
    const float* W0 = (const float*)d_in[1];
    const float* b0 = (const float*)d_in[2];
    const float* W1 = (const float*)d_in[3];
    const float* b1 = (const float*)d_in[4];
    float* out = (float*)d_out;

    char* ws = (char*)d_ws;
    u32* prog  = (u32*)ws;
    u32* hbuf0 = (u32*)(ws + HBUF0_OFF);
    u32* hbuf1 = (u32*)(ws + HBUF1_OFF);
    u32* xring = (u32*)(ws + XRING_OFF);

    if (ws_size < WS_NEEDED) return;

    // Zero rings+prog each call: tag 0 == step 0 gives h(0)=0 for free and
    // clears stale tags from the previous replay.
    hipMemsetAsync(d_ws, 0, WS_NEEDED, stream);

    lstm_fused<<<32, 512, 0, stream>>>(x, W0, b0, W1, b1, prog, hbuf0, hbuf1, xring, out);
}